// Round 1
// 55.022 us; speedup vs baseline: 1.0861x; 1.0861x over previous
//
#include <hip/hip_runtime.h>

// ExactWeightedDTM: B=4, C=1, H=W=64, N=4096, M0=0.01, R=2.0.
// R=2 => dists_pow == d2 (exact integer squared distance). The reference's
// sort/cumsum/clamp is EXACTLY a sequential scan in nondecreasing d2:
//   take = clamp(m_target - cum, 0, w);  wsum += take*d2;  cum += w;
// (tie groups are order-independent since they share the d2 multiplier).
//
// R5 = R4 with two serial-path cuts (counters show dtm_kernel below the
// 39 us harness fills -> kernel is latency-bound at ~2-3 us; attack the
// remaining critical path):
//  (a) Scan is fully compile-time unrolled: TAB entries fold to constants,
//      offsets are rebased to the window corner so every element is ONE
//      ds_read_b32 with a 16-bit immediate offset (no s_load of the table,
//      no per-element v_add address calc).
//  (b) Per-block LDS staging shrinks from the whole 94x96 padded image
//      (36 KB) to the 36x96 window actually needed by the block's 4 rows
//      (13.5 KB). Zero-writes touch ONLY pad quads and copy-writes ONLY
//      interior quads (disjoint) -> the zero/copy barrier is dropped
//      (2 barriers -> 1). Total-mass reduction is kept bit-identical.
// Early exit via __all ballot in 16-element chunks. Exact global-memory
// fallback (never runs for this input) preserves correctness.

#define TABN 709
#define WROWS 36             // window rows: image rows y0-16 .. y0+19
#define WSTRIDE 96           // padded row stride (floats), float4-friendly
#define WFLOATS (WROWS * WSTRIDE)   // 3456 floats = 13.5 KB
#define WQUADS  (WFLOATS / 4)       // 864 float4

struct Tab { int v[TABN]; };
static constexpr Tab make_tab() {
    Tab t{};
    int cnt[226] = {};
    for (int dy = -15; dy <= 15; dy++)
        for (int dx = -15; dx <= 15; dx++) {
            const int d2 = dy * dy + dx * dx;
            if (d2 <= 225) cnt[d2]++;
        }
    int pos[226] = {}; int run = 0;
    for (int d = 0; d < 226; d++) { pos[d] = run; run += cnt[d]; }
    for (int dy = -15; dy <= 15; dy++)
        for (int dx = -15; dx <= 15; dx++) {
            const int d2 = dy * dy + dx * dx;
            if (d2 <= 225)
                t.v[pos[d2]++] = (((dy + 15) * WSTRIDE + (dx + 15)) << 8) | d2;
        }
    return t;
}
__device__ constexpr Tab TAB = make_tab();

__global__ __launch_bounds__(256) void dtm_kernel(const float* __restrict__ images,
                                                  float* __restrict__ out) {
    __shared__ float pimg[WFLOATS];
    __shared__ float red4[4];

    const int tid = threadIdx.x;
    const int gid = blockIdx.x * 256 + tid;
    const int b   = gid >> 12;        // 4096 px/batch, 16 blocks/batch
    const int pix = gid & 4095;
    const int py  = pix >> 6;
    const int px  = pix & 63;
    const int y0  = (blockIdx.x & 15) << 2;   // first image row of this block

    float4* pv = (float4*)pimg;

    // 1) zero ONLY the pad quads of the window (disjoint from copy targets).
    //    window row r holds image row iy = y0-16+r; quads q=4..19 are the
    //    interior (image cols 0..63) and are written by the copy phase.
#pragma unroll
    for (int i = 0; i < 4; i++) {
        const int s = tid + 256 * i;
        if (s < WQUADS) {
            const int r  = s / 24;            // 24 quads per window row
            const int q  = s - r * 24;
            const int iy = y0 - 16 + r;
            const bool interior = (iy >= 0) & (iy <= 63) & (q >= 4) & (q < 20);
            if (!interior) pv[s] = make_float4(0.f, 0.f, 0.f, 0.f);
        }
    }

    // 2) full-image read: accumulate total mass; stage in-window rows to LDS.
    //    (reduction order identical to R4 -> bitwise-identical m_target)
    const float4* src = (const float4*)(images + (b << 12));
    float partial = 0.f;
#pragma unroll
    for (int i = 0; i < 4; i++) {
        const int fi = tid + 256 * i;     // float4 index 0..1023
        const int iy = fi >> 4;
        const int xq = fi & 15;
        const float4 v = src[fi];
        const int r = iy - y0 + 16;
        if (r >= 0 && r < WROWS) pv[r * 24 + 4 + xq] = v;
        partial += v.x + v.y + v.z + v.w;
    }
#pragma unroll
    for (int m = 32; m >= 1; m >>= 1) partial += __shfl_xor(partial, m, 64);
    if ((tid & 63) == 0) red4[tid >> 6] = partial;
    __syncthreads();                          // single barrier: LDS image + red4
    const float total    = red4[0] + red4[1] + red4[2] + red4[3];
    const float m_target = 0.01f * total;

    // 3) sequential scan in nondecreasing d2, fully unrolled at compile time.
    //    base is rebased to the window corner of the (dy=-15,dx=-15) offset so
    //    all 709 entries fold to ds_read_b32 ... offset:<imm in [0,11640]>.
    const float* base = pimg + (py - y0 + 1) * WSTRIDE + (px + 1);
    float cum = 0.f, wd = 0.f;
    bool done = false;
#pragma unroll
    for (int c = 0; c < 704; c += 16) {
#pragma unroll
        for (int i = 0; i < 16; i++) {
            const int v      = TAB.v[c + i];         // compile-time constant
            const float w    = base[v >> 8];
            const float take = fminf(fmaxf(m_target - cum, 0.f), w);
            wd  += take * (float)(v & 255);
            cum += w;
        }
        if (__all(cum >= m_target)) { done = true; break; }
    }
    if (!done) {
#pragma unroll
        for (int i = 704; i < TABN; i++) {           // tail: 5 entries (d2=225)
            const int v      = TAB.v[i];
            const float w    = base[v >> 8];
            const float take = fminf(fmaxf(m_target - cum, 0.f), w);
            wd  += take * (float)(v & 255);
            cum += w;
        }
    }

    float ans = 0.f;
    if (total > 0.f) {
        if (cum < m_target) {
            // Exact fallback over the full image from GLOBAL memory (never
            // runs for this input): binary-search min T with F(T) >= m_target,
            // then strict-below sum + partial mass at T.
            const float* img = images + (b << 12);
            int lo = -1, hi = 7938;
            while (hi - lo > 1) {
                const int mid = lo + ((hi - lo) >> 1);
                float s = 0.f;
                for (int p = 0; p < 4096; p++) {
                    const int dy = (p >> 6) - py, dx = (p & 63) - px;
                    if (dy * dy + dx * dx <= mid) s += img[p];
                }
                if (s >= m_target) hi = mid; else lo = mid;
            }
            const int T = hi;
            float ml = 0.f, wdl = 0.f;
            for (int p = 0; p < 4096; p++) {
                const int dy = (p >> 6) - py, dx = (p & 63) - px;
                const int dd = dy * dy + dx * dx;
                if (dd < T) {
                    const float wv = img[p];
                    ml += wv; wdl += wv * (float)dd;
                }
            }
            float rem = m_target - ml;
            if (rem < 0.f) rem = 0.f;
            wd = wdl + rem * (float)T;
        }
        ans = sqrtf(wd / m_target);
    }
    out[gid] = ans;
}

extern "C" void kernel_launch(void* const* d_in, const int* in_sizes, int n_in,
                              void* d_out, int out_size, void* d_ws, size_t ws_size,
                              hipStream_t stream) {
    (void)in_sizes; (void)n_in; (void)d_ws; (void)ws_size; (void)out_size;
    const float* images = (const float*)d_in[0];
    float* out = (float*)d_out;
    // 16384 pixels, one thread each: 64 blocks x 256 threads.
    dtm_kernel<<<dim3(64), dim3(256), 0, stream>>>(images, out);
}